// Round 1
// baseline (95.068 us; speedup 1.0000x reference)
//
#include <hip/hip_runtime.h>
#include <math.h>

constexpr int NT = 256;          // threads per block
constexpr int DIMV = 256;        // volume D=H=W
constexpr int NSAMP_MAX = 2048;  // n

__global__ __launch_bounds__(NT) void psf_sample_kernel(
    const float* __restrict__ vol,         // [256^3]
    const float* __restrict__ sampleGrid,  // [B,3]
    const float* __restrict__ ax,          // [B,6]  (v[3], t[3])
    const float* __restrict__ bound,       // [B,2,3]
    const float* __restrict__ invcov,      // [B,3,3]
    const float* __restrict__ xyz,         // [B,n,3]
    float* __restrict__ out,               // [B]
    int n)
{
    const int b   = blockIdx.x;
    const int tid = threadIdx.x;

    __shared__ float s_xyz[NSAMP_MAX * 3];   // 24 KB
    __shared__ float s_par[16];
    __shared__ float s_red[2 * (NT / 64)];

    if (tid == 0) {
        // axisangle2mat
        const float v0 = ax[b*6+0], v1 = ax[b*6+1], v2 = ax[b*6+2];
        const float t0 = ax[b*6+3], t1 = ax[b*6+4], t2 = ax[b*6+5];
        const float theta = sqrtf(v0*v0 + v1*v1 + v2*v2 + 1e-12f);
        const float inv = 1.0f / theta;
        const float kx = v0*inv, ky = v1*inv, kz = v2*inv;
        const float s = sinf(theta);
        const float c = 1.0f - cosf(theta);
        // R = I + s*K + c*K^2
        const float R00 = 1.0f - c*(ky*ky + kz*kz);
        const float R01 = -s*kz + c*kx*ky;
        const float R02 =  s*ky + c*kx*kz;
        const float R10 =  s*kz + c*kx*ky;
        const float R11 = 1.0f - c*(kx*kx + kz*kz);
        const float R12 = -s*kx + c*ky*kz;
        const float R20 = -s*ky + c*kx*kz;
        const float R21 =  s*kx + c*ky*kz;
        const float R22 = 1.0f - c*(kx*kx + ky*ky);
        const float g0 = sampleGrid[b*3+0] + t0;
        const float g1 = sampleGrid[b*3+1] + t1;
        const float g2 = sampleGrid[b*3+2] + t2;
        s_par[0] = R00*g0 + R01*g1 + R02*g2;   // mat_sampleGrid
        s_par[1] = R10*g0 + R11*g1 + R12*g2;
        s_par[2] = R20*g0 + R21*g1 + R22*g2;
        s_par[3] = (bound[b*6+3] - bound[b*6+0]) * 0.5f;  // half
        s_par[4] = (bound[b*6+4] - bound[b*6+1]) * 0.5f;
        s_par[5] = (bound[b*6+5] - bound[b*6+2]) * 0.5f;
        #pragma unroll
        for (int j = 0; j < 9; ++j) s_par[6 + j] = invcov[b*9 + j];
    }

    // Stage this batch's xyz into LDS, coalesced float4 loads.
    {
        const int nflt = n * 3;
        const int nvec = nflt >> 2;  // divisible for n=2048
        const float4* __restrict__ src =
            reinterpret_cast<const float4*>(xyz + (size_t)b * nflt);
        float4* dst = reinterpret_cast<float4*>(s_xyz);
        for (int i = tid; i < nvec; i += NT) dst[i] = src[i];
        for (int i = (nvec << 2) + tid; i < nflt; i += NT)
            s_xyz[i] = xyz[(size_t)b * nflt + i];
    }
    __syncthreads();

    const float ms0 = s_par[0], ms1 = s_par[1], ms2 = s_par[2];
    const float h0  = s_par[3], h1  = s_par[4], h2  = s_par[5];
    const float M00 = s_par[6],  M01 = s_par[7],  M02 = s_par[8];
    const float M10 = s_par[9],  M11 = s_par[10], M12 = s_par[11];
    const float M20 = s_par[12], M21 = s_par[13], M22 = s_par[14];

    float sum_wx = 0.0f, sum_w = 0.0f;

    for (int i = tid; i < n; i += NT) {
        const float rx = s_xyz[i*3 + 0];
        const float ry = s_xyz[i*3 + 1];
        const float rz = s_xyz[i*3 + 2];
        // 2*sigmoid(x)-1
        const float sx = 2.0f / (1.0f + expf(-rx)) - 1.0f;
        const float sy = 2.0f / (1.0f + expf(-ry)) - 1.0f;
        const float sz = 2.0f / (1.0f + expf(-rz)) - 1.0f;
        const float bp0 = sx * h0, bp1 = sy * h1, bp2 = sz * h2;

        const float px = ms0 + bp0, py = ms1 + bp1, pz = ms2 + bp2;

        // grid = 2*(p/255 - 0.5); i? = ((g+1)*256 - 1)*0.5  (match ref ops)
        const float gx = 2.0f * (px * (1.0f/255.0f) - 0.5f);
        const float gy = 2.0f * (py * (1.0f/255.0f) - 0.5f);
        const float gz = 2.0f * (pz * (1.0f/255.0f) - 0.5f);
        const float ix = ((gx + 1.0f) * 256.0f - 1.0f) * 0.5f;
        const float iy = ((gy + 1.0f) * 256.0f - 1.0f) * 0.5f;
        const float iz = ((gz + 1.0f) * 256.0f - 1.0f) * 0.5f;

        const float x0f = floorf(ix), y0f = floorf(iy), z0f = floorf(iz);
        const float fx = ix - x0f, fy = iy - y0f, fz = iz - z0f;
        const int x0 = (int)x0f, y0 = (int)y0f, z0 = (int)z0f;
        const int x1 = x0 + 1, y1 = y0 + 1, z1 = z0 + 1;

        const bool vx0 = (x0 >= 0) & (x0 < DIMV);
        const bool vx1 = (x1 >= 0) & (x1 < DIMV);
        const bool vy0 = (y0 >= 0) & (y0 < DIMV);
        const bool vy1 = (y1 >= 0) & (y1 < DIMV);
        const bool vz0 = (z0 >= 0) & (z0 < DIMV);
        const bool vz1 = (z1 >= 0) & (z1 < DIMV);

        const int cx0 = min(max(x0, 0), DIMV-1), cx1 = min(max(x1, 0), DIMV-1);
        const int cy0 = min(max(y0, 0), DIMV-1), cy1 = min(max(y1, 0), DIMV-1);
        const int cz0 = min(max(z0, 0), DIMV-1), cz1 = min(max(z1, 0), DIMV-1);

        const float wx0 = 1.0f - fx, wx1 = fx;
        const float wy0 = 1.0f - fy, wy1 = fy;
        const float wz0 = 1.0f - fz, wz1 = fz;

        const int base_z0 = cz0 * DIMV, base_z1 = cz1 * DIMV;
        const int r00 = (base_z0 + cy0) * DIMV;
        const int r01 = (base_z0 + cy1) * DIMV;
        const int r10 = (base_z1 + cy0) * DIMV;
        const int r11 = (base_z1 + cy1) * DIMV;

        float val = 0.0f;
        val += (vz0 & vy0 & vx0) ? vol[r00 + cx0] * (wz0*wy0*wx0) : 0.0f;
        val += (vz0 & vy0 & vx1) ? vol[r00 + cx1] * (wz0*wy0*wx1) : 0.0f;
        val += (vz0 & vy1 & vx0) ? vol[r01 + cx0] * (wz0*wy1*wx0) : 0.0f;
        val += (vz0 & vy1 & vx1) ? vol[r01 + cx1] * (wz0*wy1*wx1) : 0.0f;
        val += (vz1 & vy0 & vx0) ? vol[r10 + cx0] * (wz1*wy0*wx0) : 0.0f;
        val += (vz1 & vy0 & vx1) ? vol[r10 + cx1] * (wz1*wy0*wx1) : 0.0f;
        val += (vz1 & vy1 & vx0) ? vol[r11 + cx0] * (wz1*wy1*wx0) : 0.0f;
        val += (vz1 & vy1 & vx1) ? vol[r11 + cx1] * (wz1*wy1*wx1) : 0.0f;

        // q = bp' M bp ; w = exp(-q/2)
        const float q = bp0 * (M00*bp0 + M01*bp1 + M02*bp2)
                      + bp1 * (M10*bp0 + M11*bp1 + M12*bp2)
                      + bp2 * (M20*bp0 + M21*bp1 + M22*bp2);
        const float w = expf(-0.5f * q);
        sum_w  += w;
        sum_wx += w * val;
    }

    // wave64 reduction
    #pragma unroll
    for (int off = 32; off > 0; off >>= 1) {
        sum_wx += __shfl_down(sum_wx, off);
        sum_w  += __shfl_down(sum_w,  off);
    }
    const int wave = tid >> 6;
    const int lane = tid & 63;
    if (lane == 0) { s_red[wave*2] = sum_wx; s_red[wave*2+1] = sum_w; }
    __syncthreads();
    if (tid == 0) {
        float twx = 0.0f, tw = 0.0f;
        #pragma unroll
        for (int wv = 0; wv < NT/64; ++wv) { twx += s_red[wv*2]; tw += s_red[wv*2+1]; }
        out[b] = twx / tw;
    }
}

extern "C" void kernel_launch(void* const* d_in, const int* in_sizes, int n_in,
                              void* d_out, int out_size, void* d_ws, size_t ws_size,
                              hipStream_t stream) {
    const float* vol        = (const float*)d_in[0];
    const float* sampleGrid = (const float*)d_in[1];
    const float* ax         = (const float*)d_in[2];
    const float* bound      = (const float*)d_in[3];
    const float* invcov     = (const float*)d_in[4];
    // d_in[5] = psf_sigma (unused by reference)
    const float* xyz        = (const float*)d_in[6];
    float* out              = (float*)d_out;

    const int B = in_sizes[1] / 3;
    const int n = in_sizes[6] / (B * 3);

    psf_sample_kernel<<<B, NT, 0, stream>>>(vol, sampleGrid, ax, bound, invcov,
                                            xyz, out, n);
}

// Round 2
// 30.364 us; speedup vs baseline: 3.1310x; 3.1310x over previous
//
#include <hip/hip_runtime.h>
#include <math.h>

constexpr int NT   = 256;   // threads per block
constexpr int DIMV = 256;   // volume D=H=W
constexpr int RS   = 8;     // staged region side (voxels)
constexpr int RROW = 9;     // padded row stride in floats (bank spread)
constexpr int RSLICE = RS * RROW;  // 72 floats per z-slice

__global__ __launch_bounds__(NT) void psf_sample_kernel(
    const float* __restrict__ vol,         // [256^3]
    const float* __restrict__ sampleGrid,  // [B,3]
    const float* __restrict__ ax,          // [B,6]  (v[3], t[3])
    const float* __restrict__ bound,       // [B,2,3]
    const float* __restrict__ invcov,      // [B,3,3] (symmetric)
    const float* __restrict__ xyz,         // [B,n,3]
    float* __restrict__ out,               // [B]
    int n)
{
    const int b   = blockIdx.x;
    const int tid = threadIdx.x;

    __shared__ float s_vol[RS * RSLICE];      // 576 floats = 2304 B
    __shared__ float s_red[2 * (NT / 64)];

    // ---- per-block params, computed redundantly by all threads (uniform) ----
    const float v0 = ax[b*6+0], v1 = ax[b*6+1], v2 = ax[b*6+2];
    const float t0 = ax[b*6+3], t1 = ax[b*6+4], t2 = ax[b*6+5];
    const float theta = sqrtf(v0*v0 + v1*v1 + v2*v2 + 1e-12f);
    const float inv = 1.0f / theta;
    const float kx = v0*inv, ky = v1*inv, kz = v2*inv;
    const float sn = sinf(theta);
    const float cn = 1.0f - cosf(theta);
    const float R00 = 1.0f - cn*(ky*ky + kz*kz);
    const float R01 = -sn*kz + cn*kx*ky;
    const float R02 =  sn*ky + cn*kx*kz;
    const float R10 =  sn*kz + cn*kx*ky;
    const float R11 = 1.0f - cn*(kx*kx + kz*kz);
    const float R12 = -sn*kx + cn*ky*kz;
    const float R20 = -sn*ky + cn*kx*kz;
    const float R21 =  sn*kx + cn*ky*kz;
    const float R22 = 1.0f - cn*(kx*kx + ky*ky);
    const float g0 = sampleGrid[b*3+0] + t0;
    const float g1 = sampleGrid[b*3+1] + t1;
    const float g2 = sampleGrid[b*3+2] + t2;
    const float ms0 = R00*g0 + R01*g1 + R02*g2;
    const float ms1 = R10*g0 + R11*g1 + R12*g2;
    const float ms2 = R20*g0 + R21*g1 + R22*g2;
    const float h0 = (bound[b*6+3] - bound[b*6+0]) * 0.5f;
    const float h1 = (bound[b*6+4] - bound[b*6+1]) * 0.5f;
    const float h2 = (bound[b*6+5] - bound[b*6+2]) * 0.5f;
    const float M00 = invcov[b*9+0], M01 = invcov[b*9+1], M02 = invcov[b*9+2];
    const float M11 = invcov[b*9+4], M12 = invcov[b*9+5], M22 = invcov[b*9+8];

    // voxel coords: i = p*(256/255) - 0.5  (algebraic reduction of the ref's
    // grid normalize + unnormalize round-trip)
    const float kk = 256.0f / 255.0f;
    const float cix = ms0 * kk - 0.5f;   // center in index space
    const float ciy = ms1 * kk - 0.5f;
    const float ciz = ms2 * kk - 0.5f;
    const float hx = h0 * kk, hy = h1 * kk, hz = h2 * kk;

    // staged-region base; span fits RS=8 iff 2*h*kk + 2 < 8  (h <= 2.5 here)
    const int bx = (int)floorf(cix - hx - 1e-3f);
    const int by = (int)floorf(ciy - hy - 1e-3f);
    const int bz = (int)floorf(ciz - hz - 1e-3f);
    const bool fast = (hx <= 2.9f) && (hy <= 2.9f) && (hz <= 2.9f);

    if (fast) {
        for (int idx = tid; idx < RS*RS*RS; idx += NT) {
            const int lx = idx & 7, ly = (idx >> 3) & 7, lz = idx >> 6;
            const int gx = bx + lx, gy = by + ly, gz = bz + lz;
            float v = 0.0f;
            if ((unsigned)gx < (unsigned)DIMV && (unsigned)gy < (unsigned)DIMV &&
                (unsigned)gz < (unsigned)DIMV)
                v = vol[((size_t)gz * DIMV + gy) * DIMV + gx];
            s_vol[(lz * RS + ly) * RROW + lx] = v;
        }
    }
    __syncthreads();

    float sum_wx = 0.0f, sum_w = 0.0f;
    const float* __restrict__ xb = xyz + (size_t)b * n * 3;

    for (int i = tid; i < n; i += NT) {
        const float rx = xb[i*3 + 0];
        const float ry = xb[i*3 + 1];
        const float rz = xb[i*3 + 2];
        // 2*sigmoid(r)-1 = (1-e)/(1+e), e = exp(-r)
        const float ex = __expf(-rx), ey = __expf(-ry), ez = __expf(-rz);
        const float sx = (1.0f - ex) * __builtin_amdgcn_rcpf(1.0f + ex);
        const float sy = (1.0f - ey) * __builtin_amdgcn_rcpf(1.0f + ey);
        const float sz = (1.0f - ez) * __builtin_amdgcn_rcpf(1.0f + ez);
        const float bp0 = sx * h0, bp1 = sy * h1, bp2 = sz * h2;

        const float ixf = fmaf(bp0, kk, cix);
        const float iyf = fmaf(bp1, kk, ciy);
        const float izf = fmaf(bp2, kk, ciz);

        const float x0f = floorf(ixf), y0f = floorf(iyf), z0f = floorf(izf);
        const float fx = ixf - x0f, fy = iyf - y0f, fz = izf - z0f;

        float val;
        if (fast) {
            // local indices, clamped defensively (should already be in range)
            const int lx = min(max((int)x0f - bx, 0), RS - 2);
            const int ly = min(max((int)y0f - by, 0), RS - 2);
            const int lz = min(max((int)z0f - bz, 0), RS - 2);
            const float* p = &s_vol[(lz * RS + ly) * RROW + lx];
            const float v000 = p[0],              v001 = p[1];
            const float v010 = p[RROW],           v011 = p[RROW + 1];
            const float v100 = p[RSLICE],         v101 = p[RSLICE + 1];
            const float v110 = p[RSLICE + RROW],  v111 = p[RSLICE + RROW + 1];
            const float a00 = fmaf(fx, v001 - v000, v000);
            const float a01 = fmaf(fx, v011 - v010, v010);
            const float a10 = fmaf(fx, v101 - v100, v100);
            const float a11 = fmaf(fx, v111 - v110, v110);
            const float a0  = fmaf(fy, a01 - a00, a00);
            const float a1  = fmaf(fy, a11 - a10, a10);
            val = fmaf(fz, a1 - a0, a0);
        } else {
            // slow fallback: global gathers with masks (never expected here)
            const int x0 = (int)x0f, y0 = (int)y0f, z0 = (int)z0f;
            const int x1 = x0 + 1, y1 = y0 + 1, z1 = z0 + 1;
            const bool vx0 = (unsigned)x0 < (unsigned)DIMV;
            const bool vx1 = (unsigned)x1 < (unsigned)DIMV;
            const bool vy0 = (unsigned)y0 < (unsigned)DIMV;
            const bool vy1 = (unsigned)y1 < (unsigned)DIMV;
            const bool vz0 = (unsigned)z0 < (unsigned)DIMV;
            const bool vz1 = (unsigned)z1 < (unsigned)DIMV;
            const int cx0 = min(max(x0,0),DIMV-1), cx1 = min(max(x1,0),DIMV-1);
            const int cy0 = min(max(y0,0),DIMV-1), cy1 = min(max(y1,0),DIMV-1);
            const int cz0 = min(max(z0,0),DIMV-1), cz1 = min(max(z1,0),DIMV-1);
            const float wx0 = 1.0f-fx, wx1 = fx, wy0 = 1.0f-fy, wy1 = fy;
            const float wz0 = 1.0f-fz, wz1 = fz;
            const int r00 = (cz0*DIMV + cy0)*DIMV, r01 = (cz0*DIMV + cy1)*DIMV;
            const int r10 = (cz1*DIMV + cy0)*DIMV, r11 = (cz1*DIMV + cy1)*DIMV;
            val  = (vz0&&vy0&&vx0) ? vol[r00+cx0]*(wz0*wy0*wx0) : 0.0f;
            val += (vz0&&vy0&&vx1) ? vol[r00+cx1]*(wz0*wy0*wx1) : 0.0f;
            val += (vz0&&vy1&&vx0) ? vol[r01+cx0]*(wz0*wy1*wx0) : 0.0f;
            val += (vz0&&vy1&&vx1) ? vol[r01+cx1]*(wz0*wy1*wx1) : 0.0f;
            val += (vz1&&vy0&&vx0) ? vol[r10+cx0]*(wz1*wy0*wx0) : 0.0f;
            val += (vz1&&vy0&&vx1) ? vol[r10+cx1]*(wz1*wy0*wx1) : 0.0f;
            val += (vz1&&vy1&&vx0) ? vol[r11+cx0]*(wz1*wy1*wx0) : 0.0f;
            val += (vz1&&vy1&&vx1) ? vol[r11+cx1]*(wz1*wy1*wx1) : 0.0f;
        }

        // q = bp' M bp, M symmetric
        const float q = M00*bp0*bp0 + M11*bp1*bp1 + M22*bp2*bp2
                      + 2.0f*(M01*bp0*bp1 + M02*bp0*bp2 + M12*bp1*bp2);
        const float w = __expf(-0.5f * q);
        sum_w  += w;
        sum_wx = fmaf(w, val, sum_wx);
    }

    // wave64 reduction
    #pragma unroll
    for (int off = 32; off > 0; off >>= 1) {
        sum_wx += __shfl_down(sum_wx, off);
        sum_w  += __shfl_down(sum_w,  off);
    }
    const int wave = tid >> 6;
    const int lane = tid & 63;
    if (lane == 0) { s_red[wave*2] = sum_wx; s_red[wave*2+1] = sum_w; }
    __syncthreads();
    if (tid == 0) {
        float twx = 0.0f, tw = 0.0f;
        #pragma unroll
        for (int wv = 0; wv < NT/64; ++wv) { twx += s_red[wv*2]; tw += s_red[wv*2+1]; }
        out[b] = twx / tw;
    }
}

extern "C" void kernel_launch(void* const* d_in, const int* in_sizes, int n_in,
                              void* d_out, int out_size, void* d_ws, size_t ws_size,
                              hipStream_t stream) {
    const float* vol        = (const float*)d_in[0];
    const float* sampleGrid = (const float*)d_in[1];
    const float* ax         = (const float*)d_in[2];
    const float* bound      = (const float*)d_in[3];
    const float* invcov     = (const float*)d_in[4];
    // d_in[5] = psf_sigma (unused by reference)
    const float* xyz        = (const float*)d_in[6];
    float* out              = (float*)d_out;

    const int B = in_sizes[1] / 3;
    const int n = in_sizes[6] / (B * 3);

    psf_sample_kernel<<<B, NT, 0, stream>>>(vol, sampleGrid, ax, bound, invcov,
                                            xyz, out, n);
}

// Round 3
// 30.018 us; speedup vs baseline: 3.1670x; 1.0115x over previous
//
#include <hip/hip_runtime.h>
#include <math.h>

constexpr int NT   = 256;   // threads per block
constexpr int DIMV = 256;   // volume D=H=W
constexpr int RS   = 8;     // staged region side (voxels)
constexpr int RROW = 9;     // padded row stride in floats
constexpr int RSLICE = RS * RROW;  // 72 floats per z-slice

__global__ __launch_bounds__(NT) void psf_sample_kernel(
    const float* __restrict__ vol,         // [256^3]
    const float* __restrict__ sampleGrid,  // [B,3]
    const float* __restrict__ ax,          // [B,6]  (v[3], t[3])
    const float* __restrict__ bound,       // [B,2,3]
    const float* __restrict__ invcov,      // [B,3,3] (symmetric)
    const float* __restrict__ xyz,         // [B,n,3]
    float* __restrict__ out,               // [B]
    int n)
{
    const int b   = blockIdx.x;
    const int tid = threadIdx.x;

    __shared__ float s_vol[RS * RSLICE];      // 576 floats = 2304 B
    __shared__ float s_red[2 * (NT / 64)];

    // ---- per-block params, computed redundantly by all threads (uniform) ----
    const float v0 = ax[b*6+0], v1 = ax[b*6+1], v2 = ax[b*6+2];
    const float t0 = ax[b*6+3], t1 = ax[b*6+4], t2 = ax[b*6+5];
    const float theta = sqrtf(v0*v0 + v1*v1 + v2*v2 + 1e-12f);
    const float inv = 1.0f / theta;
    const float kx = v0*inv, ky = v1*inv, kz = v2*inv;
    const float sn = sinf(theta);
    const float cn = 1.0f - cosf(theta);
    const float R00 = 1.0f - cn*(ky*ky + kz*kz);
    const float R01 = -sn*kz + cn*kx*ky;
    const float R02 =  sn*ky + cn*kx*kz;
    const float R10 =  sn*kz + cn*kx*ky;
    const float R11 = 1.0f - cn*(kx*kx + kz*kz);
    const float R12 = -sn*kx + cn*ky*kz;
    const float R20 = -sn*ky + cn*kx*kz;
    const float R21 =  sn*kx + cn*ky*kz;
    const float R22 = 1.0f - cn*(kx*kx + ky*ky);
    const float g0 = sampleGrid[b*3+0] + t0;
    const float g1 = sampleGrid[b*3+1] + t1;
    const float g2 = sampleGrid[b*3+2] + t2;
    const float ms0 = R00*g0 + R01*g1 + R02*g2;
    const float ms1 = R10*g0 + R11*g1 + R12*g2;
    const float ms2 = R20*g0 + R21*g1 + R22*g2;
    const float h0 = (bound[b*6+3] - bound[b*6+0]) * 0.5f;
    const float h1 = (bound[b*6+4] - bound[b*6+1]) * 0.5f;
    const float h2 = (bound[b*6+5] - bound[b*6+2]) * 0.5f;
    const float M00 = invcov[b*9+0], M01 = invcov[b*9+1], M02 = invcov[b*9+2];
    const float M11 = invcov[b*9+4], M12 = invcov[b*9+5], M22 = invcov[b*9+8];

    // quadratic form folded: w = exp(-0.5 * bp'M bp), bp = s*h
    //   => w = __expf(B00 sx^2 + B11 sy^2 + B22 sz^2 + B01 sx sy + B02 sx sz + B12 sy sz)
    const float B00 = -0.5f * M00 * h0 * h0;
    const float B11 = -0.5f * M11 * h1 * h1;
    const float B22 = -0.5f * M22 * h2 * h2;
    const float B01 = -M01 * h0 * h1;
    const float B02 = -M02 * h0 * h2;
    const float B12 = -M12 * h1 * h2;

    // voxel coords: i = p*(256/255) - 0.5  (algebraic reduction of the ref's
    // grid normalize + unnormalize round-trip)
    const float kk = 256.0f / 255.0f;
    const float cix = ms0 * kk - 0.5f;
    const float ciy = ms1 * kk - 0.5f;
    const float ciz = ms2 * kk - 0.5f;
    const float hx = h0 * kk, hy = h1 * kk, hz = h2 * kk;

    const int bx = (int)floorf(cix - hx - 1e-3f);
    const int by = (int)floorf(ciy - hy - 1e-3f);
    const int bz = (int)floorf(ciz - hz - 1e-3f);
    // fast path valid iff local index span fits RS-2: needs 2h*kk < 5.8
    const bool fast = (hx <= 2.9f) && (hy <= 2.9f) && (hz <= 2.9f);

    if (fast) {
        #pragma unroll
        for (int pass = 0; pass < (RS*RS*RS)/NT; ++pass) {
            const int idx = pass * NT + tid;
            const int lx = idx & 7, ly = (idx >> 3) & 7, lz = idx >> 6;
            const int gx = bx + lx, gy = by + ly, gz = bz + lz;
            float v = 0.0f;
            if ((unsigned)gx < (unsigned)DIMV && (unsigned)gy < (unsigned)DIMV &&
                (unsigned)gz < (unsigned)DIMV)
                v = vol[((size_t)gz * DIMV + gy) * DIMV + gx];
            s_vol[(lz * RS + ly) * RROW + lx] = v;
        }
    }
    __syncthreads();

    float sum_wx = 0.0f, sum_w = 0.0f;

    auto doSample = [&](float rx, float ry, float rz) {
        // s = 2*sigmoid(r)-1 = (1-e)/(1+e), e = exp(-r)
        const float ex = __expf(-rx), ey = __expf(-ry), ez = __expf(-rz);
        const float sx = (1.0f - ex) * __builtin_amdgcn_rcpf(1.0f + ex);
        const float sy = (1.0f - ey) * __builtin_amdgcn_rcpf(1.0f + ey);
        const float sz = (1.0f - ez) * __builtin_amdgcn_rcpf(1.0f + ez);

        const float ixf = fmaf(sx, hx, cix);
        const float iyf = fmaf(sy, hy, ciy);
        const float izf = fmaf(sz, hz, ciz);
        const float x0f = floorf(ixf), y0f = floorf(iyf), z0f = floorf(izf);
        const float fx = ixf - x0f, fy = iyf - y0f, fz = izf - z0f;

        float val;
        if (fast) {
            // in-range by construction (margin proof in R2 notes): lx,ly,lz in [0,6]
            const int lx = (int)x0f - bx;
            const int ly = (int)y0f - by;
            const int lz = (int)z0f - bz;
            const float* p = &s_vol[(lz * RS + ly) * RROW + lx];
            const float v000 = p[0],              v001 = p[1];
            const float v010 = p[RROW],           v011 = p[RROW + 1];
            const float v100 = p[RSLICE],         v101 = p[RSLICE + 1];
            const float v110 = p[RSLICE + RROW],  v111 = p[RSLICE + RROW + 1];
            const float a00 = fmaf(fx, v001 - v000, v000);
            const float a01 = fmaf(fx, v011 - v010, v010);
            const float a10 = fmaf(fx, v101 - v100, v100);
            const float a11 = fmaf(fx, v111 - v110, v110);
            const float a0  = fmaf(fy, a01 - a00, a00);
            const float a1  = fmaf(fy, a11 - a10, a10);
            val = fmaf(fz, a1 - a0, a0);
        } else {
            const int x0 = (int)x0f, y0 = (int)y0f, z0 = (int)z0f;
            const int x1 = x0 + 1, y1 = y0 + 1, z1 = z0 + 1;
            const bool vx0 = (unsigned)x0 < (unsigned)DIMV;
            const bool vx1 = (unsigned)x1 < (unsigned)DIMV;
            const bool vy0 = (unsigned)y0 < (unsigned)DIMV;
            const bool vy1 = (unsigned)y1 < (unsigned)DIMV;
            const bool vz0 = (unsigned)z0 < (unsigned)DIMV;
            const bool vz1 = (unsigned)z1 < (unsigned)DIMV;
            const int cx0 = min(max(x0,0),DIMV-1), cx1 = min(max(x1,0),DIMV-1);
            const int cy0 = min(max(y0,0),DIMV-1), cy1 = min(max(y1,0),DIMV-1);
            const int cz0 = min(max(z0,0),DIMV-1), cz1 = min(max(z1,0),DIMV-1);
            const float wx0 = 1.0f-fx, wx1 = fx, wy0 = 1.0f-fy, wy1 = fy;
            const float wz0 = 1.0f-fz, wz1 = fz;
            const int r00 = (cz0*DIMV + cy0)*DIMV, r01 = (cz0*DIMV + cy1)*DIMV;
            const int r10 = (cz1*DIMV + cy0)*DIMV, r11 = (cz1*DIMV + cy1)*DIMV;
            val  = (vz0&&vy0&&vx0) ? vol[r00+cx0]*(wz0*wy0*wx0) : 0.0f;
            val += (vz0&&vy0&&vx1) ? vol[r00+cx1]*(wz0*wy0*wx1) : 0.0f;
            val += (vz0&&vy1&&vx0) ? vol[r01+cx0]*(wz0*wy1*wx0) : 0.0f;
            val += (vz0&&vy1&&vx1) ? vol[r01+cx1]*(wz0*wy1*wx1) : 0.0f;
            val += (vz1&&vy0&&vx0) ? vol[r10+cx0]*(wz1*wy0*wx0) : 0.0f;
            val += (vz1&&vy0&&vx1) ? vol[r10+cx1]*(wz1*wy0*wx1) : 0.0f;
            val += (vz1&&vy1&&vx0) ? vol[r11+cx0]*(wz1*wy1*wx0) : 0.0f;
            val += (vz1&&vy1&&vx1) ? vol[r11+cx1]*(wz1*wy1*wx1) : 0.0f;
        }

        const float f = fmaf(B00, sx*sx,
                        fmaf(B11, sy*sy,
                        fmaf(B22, sz*sz,
                        fmaf(B01, sx*sy,
                        fmaf(B02, sx*sz, B12 * (sy*sz))))));
        const float w = __expf(f);
        sum_w  += w;
        sum_wx = fmaf(w, val, sum_wx);
    };

    // 4 samples per iteration via 3 coalesced float4 loads (48 B/thread)
    const int ng = n >> 2;
    const float4* __restrict__ xb4 =
        reinterpret_cast<const float4*>(xyz + (size_t)b * n * 3);
    for (int g = tid; g < ng; g += NT) {
        const float4 q0 = xb4[g*3 + 0];
        const float4 q1 = xb4[g*3 + 1];
        const float4 q2 = xb4[g*3 + 2];
        doSample(q0.x, q0.y, q0.z);
        doSample(q0.w, q1.x, q1.y);
        doSample(q1.z, q1.w, q2.x);
        doSample(q2.y, q2.z, q2.w);
    }
    // generic tail (unused when n % 4 == 0)
    const float* __restrict__ xb = xyz + (size_t)b * n * 3;
    for (int i = (ng << 2) + tid; i < n; i += NT)
        doSample(xb[i*3+0], xb[i*3+1], xb[i*3+2]);

    // wave64 reduction
    #pragma unroll
    for (int off = 32; off > 0; off >>= 1) {
        sum_wx += __shfl_down(sum_wx, off);
        sum_w  += __shfl_down(sum_w,  off);
    }
    const int wave = tid >> 6;
    const int lane = tid & 63;
    if (lane == 0) { s_red[wave*2] = sum_wx; s_red[wave*2+1] = sum_w; }
    __syncthreads();
    if (tid == 0) {
        float twx = 0.0f, tw = 0.0f;
        #pragma unroll
        for (int wv = 0; wv < NT/64; ++wv) { twx += s_red[wv*2]; tw += s_red[wv*2+1]; }
        out[b] = twx / tw;
    }
}

extern "C" void kernel_launch(void* const* d_in, const int* in_sizes, int n_in,
                              void* d_out, int out_size, void* d_ws, size_t ws_size,
                              hipStream_t stream) {
    const float* vol        = (const float*)d_in[0];
    const float* sampleGrid = (const float*)d_in[1];
    const float* ax         = (const float*)d_in[2];
    const float* bound      = (const float*)d_in[3];
    const float* invcov     = (const float*)d_in[4];
    // d_in[5] = psf_sigma (unused by reference)
    const float* xyz        = (const float*)d_in[6];
    float* out              = (float*)d_out;

    const int B = in_sizes[1] / 3;
    const int n = in_sizes[6] / (B * 3);

    psf_sample_kernel<<<B, NT, 0, stream>>>(vol, sampleGrid, ax, bound, invcov,
                                            xyz, out, n);
}